// Round 3
// baseline (306.273 us; speedup 1.0000x reference)
//
#include <hip/hip_runtime.h>
#include <cmath>

#define XR_RT   32   // r-rows per block in xred kernel
#define XR_BC   32   // b-values per block in xred kernel
#define OGROUP  8    // o-rows per block in main kernel
#define BCHUNK  16   // b-values per block in main kernel

typedef float nfloat4 __attribute__((ext_vector_type(4)));  // native vec for nontemporal builtins

// ---------------- Kernel 1: x_red[b,r] = sum_i x[b,i] * mask[r,i] ----------------
// Tiled (32 r x 32 b) so the grid is 512 blocks (2/CU) instead of 256 (1/CU).
// mask rows + transposed x tile staged in LDS; compute reads are conflict-free
// (ms: banks (r+i)&31 distinct across half-wave; xs: float4 broadcast per half-wave).
__global__ __launch_bounds__(256) void xred_kernel(const float* __restrict__ x,
                                                   const float* __restrict__ mask,
                                                   float* __restrict__ xred) {
    __shared__ float ms[XR_RT][129];      // 16.5 KB
    __shared__ float xs[128][40];         // [i][b] transposed, pad 40: 160B rows (16B-mult), 4-way write alias
    const int tid = threadIdx.x;
    const int r0  = blockIdx.x * XR_RT;
    const int b0  = blockIdx.y * XR_BC;

    // stage 32 mask rows: 4096 floats via float4 (coalesced)
    const float4* m4 = (const float4*)(mask + (size_t)r0 * 128);
    for (int k = tid; k < XR_RT * 32; k += 256) {
        float4 v = m4[k];
        int row = k >> 5;
        int col = (k & 31) * 4;
        ms[row][col]     = v.x;
        ms[row][col + 1] = v.y;
        ms[row][col + 2] = v.z;
        ms[row][col + 3] = v.w;
    }
    // stage x transposed (coalesced global read; 4-way LDS write alias is cheap)
    for (int k = tid; k < XR_BC * 128; k += 256) {
        int b = k >> 7, i = k & 127;
        xs[i][b] = x[(size_t)(b0 + b) * 128 + i];
    }
    __syncthreads();

    const int r = tid & 31;               // lane's mask row
    const int g = tid >> 5;               // 0..7 -> b = 4g..4g+3
    float acc[4] = {0.f, 0.f, 0.f, 0.f};
    for (int i = 0; i < 128; ++i) {
        const float  m  = ms[r][i];                       // banks (r+i)&31, conflict-free
        const float4 xa = *(const float4*)&xs[i][4 * g];  // broadcast within half-wave
        acc[0] += m * xa.x; acc[1] += m * xa.y; acc[2] += m * xa.z; acc[3] += m * xa.w;
    }
    #pragma unroll
    for (int j = 0; j < 4; ++j)
        xred[(size_t)(b0 + 4 * g + j) * 128 + (r0 + r)] = acc[j];
}

// ---------------- Kernel 2: z, postacts, y ----------------
// Thread owns an i-quad of one o-row (float4 nontemporal store). Block = 8 o-rows.
// fun_id state hoisted to registers. b-loop: explicit xr prefetch + unroll 2 so two
// independent compute+swizzle chains overlap (hides ds_swizzle / L2-load latency).
__global__ __launch_bounds__(256) void kan_main(const float4* __restrict__ xred4,
                                                const float4* __restrict__ affine,
                                                const int* __restrict__ fun_ids,
                                                float* __restrict__ y,
                                                float4* __restrict__ post4) {
    const int tid = threadIdx.x;
    const int oo  = tid >> 5;                 // 0..7 : o-row within block
    const int il  = tid & 31;                 // i-quad index (i = 4*il .. 4*il+3)
    const int o   = blockIdx.x * OGROUP + oo;

    // ---- hoist per-element affine + fun_id-derived state (b-invariant) ----
    float4 A[4]; int f[4];
    #pragma unroll
    for (int j = 0; j < 4; ++j) {
        A[j] = affine[(size_t)o * 128 + il * 4 + j];
        f[j] = fun_ids[(size_t)o * 128 + il * 4 + j];
    }

    bool m1[4], m2[4], m3[4], m7[4], m8[4], me[4];
    float k1[4], k2[4], An[4], Bn[4], Dd[4];
    #pragma unroll
    for (int j = 0; j < 4; ++j) {
        const int fj = f[j];
        m1[j] = (fj == 1); m2[j] = (fj == 2); m3[j] = (fj == 3);
        m7[j] = (fj == 7); m8[j] = (fj == 8);
        me[j] = (fj >= 4 && fj <= 6) || (fj == 9);
        // exp-group: arg = k1*z + k2*z^2 ; r = (An + Bn*e)/(1 + Dd*e)
        float k1v = 0.f, k2v = 0.f, Anv = 0.f, Bnv = 1.f, Ddv = 0.f;
        if      (fj == 4) { k1v = -2.f; Anv = 1.f; Bnv = -1.f; Ddv = 1.f; }  // tanh
        else if (fj == 5) { k1v = -1.f; Anv = 1.f; Bnv =  0.f; Ddv = 1.f; }  // sigmoid
        else if (fj == 6) { k2v = -1.f; }                                    // exp(-z^2)
        else if (fj == 9) { k1v =  1.f; }                                    // exp(z)
        k1[j] = k1v; k2[j] = k2v; An[j] = Anv; Bn[j] = Bnv; Dd[j] = Ddv;
    }

    const int b0 = blockIdx.y * BCHUNK;

    float4 xr = xred4[(size_t)b0 * 32 + il];   // prefetched

    #pragma unroll 2
    for (int bb = 0; bb < BCHUNK; ++bb) {
        const int b = b0 + bb;
        // prefetch next iteration's row slice (L2-resident, broadcast across blocks)
        float4 xr_n = xr;
        if (bb + 1 < BCHUNK) xr_n = xred4[(size_t)(b + 1) * 32 + il];

        const float xv[4] = {xr.x, xr.y, xr.z, xr.w};

        float p[4];
        #pragma unroll
        for (int j = 0; j < 4; ++j) {
            const float z  = fmaf(A[j].x, xv[j], A[j].y);
            const float zz = z * z;
            float pv = m1[j] ? zz : z;
            pv = m2[j] ? zz * z : pv;
            pv = m7[j] ? fabsf(z) : pv;
            const float s = __sinf(z);
            pv = m3[j] ? s : pv;
            const float arg = fminf(fmaf(k2[j], zz, k1[j] * z), 80.f);
            const float e   = __expf(arg);
            const float num = fmaf(Bn[j], e, An[j]);
            const float den = fmaf(Dd[j], e, 1.0f);
            const float r   = num * __builtin_amdgcn_rcpf(den);
            pv = me[j] ? r : pv;
            // atan: 3-term minimax on t in [0,1] (max abs err ~6e-4)
            const float az  = fabsf(z);
            const bool  big = az > 1.0f;
            const float t   = big ? __builtin_amdgcn_rcpf(az) : az;
            const float t2  = t * t;
            float q = fmaf(t2, 0.079331f, -0.288679f);
            q = fmaf(t2, q, 0.995354f);
            q = t * q;
            q = big ? 1.57079632679f - q : q;
            const float at = copysignf(q, z);
            pv = m8[j] ? at : pv;
            p[j] = fmaf(A[j].z, pv, A[j].w);
        }

        // contiguous 1 KB per wave store, streaming (no read-back) -> nontemporal
        nfloat4 pv4 = {p[0], p[1], p[2], p[3]};
        __builtin_nontemporal_store(pv4,
            reinterpret_cast<nfloat4*>(&post4[((size_t)b * 128 + o) * 32 + il]));

        // y[b,o] = sum_i postacts : xor-tree over the 32 lanes of this o-row
        float s = (p[0] + p[1]) + (p[2] + p[3]);
        s += __shfl_xor(s, 1, 64);
        s += __shfl_xor(s, 2, 64);
        s += __shfl_xor(s, 4, 64);
        s += __shfl_xor(s, 8, 64);
        s += __shfl_xor(s, 16, 64);
        if (il == 0) __builtin_nontemporal_store(s, &y[(size_t)b * 128 + o]);

        xr = xr_n;
    }
}

extern "C" void kernel_launch(void* const* d_in, const int* in_sizes, int n_in,
                              void* d_out, int out_size, void* d_ws, size_t ws_size,
                              hipStream_t stream) {
    const float* x       = (const float*)d_in[0];   // (batch, 128)
    const float* affine  = (const float*)d_in[1];   // (128, 128, 4)
    const float* mask    = (const float*)d_in[2];   // (128, 128)
    const int*   fun_ids = (const int*)d_in[3];     // (128, 128)

    const int batch = in_sizes[0] / 128;            // 4096

    float* xred     = (float*)d_ws;                 // batch*128 floats (2 MB)
    float* y        = (float*)d_out;                // batch*128
    float* postacts = y + (size_t)batch * 128;      // batch*128*128

    xred_kernel<<<dim3(128 / XR_RT, batch / XR_BC), dim3(256), 0, stream>>>(x, mask, xred);

    kan_main<<<dim3(128 / OGROUP, batch / BCHUNK), dim3(256), 0, stream>>>(
        (const float4*)xred, (const float4*)affine, fun_ids, y, (float4*)postacts);
}